// Round 8
// baseline (139.691 us; speedup 1.0000x reference)
//
#include <hip/hip_runtime.h>

// Problem constants (from reference setup_inputs)
#define B_   32
#define T_   4096
#define D_   128
#define TU   512
#define M_   8
#define O_   64      // Dout
#define DCH  8       // D-chunk per block (R8: halved -> 2 blocks/CU, 32 waves)
#define NCH  16      // number of D-chunks (D_/DCH)
#define NP   NCH     // 16 partials per batch, one per chunk (disjoint d: SAFE)
#define LD   9       // hid leading dim: 9 coprime 32 -> 2-way bank alias (free)
#define BN_EPS 1e-5f
#define UB   4       // t-loop load batch depth

// 16 B vector with 4 B alignment: x rows are 516 B so the 16 B feat windows
// are only element-aligned; this type lets the compiler emit dwordx4 legally
// (gfx950 unaligned-access-mode handles the line straddle in HW).
typedef float f4u __attribute__((ext_vector_type(4), aligned(4)));

// ws layout: partials[c][b][u][m]; NP*B_*TU*M_ floats = 8 MB
#define WS_STRIDE (B_ * TU * M_)

// ---------------------------------------------------------------------------
// K1: per-(batch b, chunk c) block, FULL T range (max over T must stay within
// one block -- R6/R7's T-split summed per-half maxes, which is wrong):
//   phase 0: zero LDS hid; fold BN+conv+fc for this 8-wide chunk
//   phase 1: scatter-max masked positive feats into LDS hid (uint bits;
//            hidden init=0 => only fv>0 matter; uint atomicMax == float max
//            for non-negative floats)
//   phase 2: partial[u][m] = biasc[m] + sum_{d in chunk} hid[u][d]*Weff[m][d]
//            stored (non-atomic, 16 B) to ws[c][b][u][m].
// Partials are disjoint in d, so the reduce's SUM is exact (R5 algebra).
//
// XCD swizzle: block i -> xcd = i&7; all 16 chunk-blocks of a batch share one
// XCD so each 516 B x-row is fetched from HBM once, reduce reads are L2-hits:
//   slot=i>>3; b=(i&7)+8*(slot&3); c=slot>>2
// ---------------------------------------------------------------------------
__global__ __launch_bounds__(1024) void fused_scatter_mm_kernel(
    const float* __restrict__ x,        // (B,T,129): [...,0]=tw, [...,1:]=feats
    const int*   __restrict__ mask,     // (B,T) as int32
    const float* __restrict__ tw_uniq,  // (B,Tu)
    const float* __restrict__ bn_gamma,
    const float* __restrict__ bn_beta,
    const float* __restrict__ bn_mean,
    const float* __restrict__ bn_var,
    const float* __restrict__ conv_w,   // (64,128)
    const float* __restrict__ conv_b,   // (64,)
    const float* __restrict__ fc_w,     // (8,64)
    const float* __restrict__ fc_b,     // (8,)
    float*       __restrict__ ws) {     // partials[c][b][u][m]
    __shared__ unsigned hid[TU * LD];   // 18,432 B -> 2 blocks/CU fits easily
    __shared__ float wsm[M_ * DCH];
    __shared__ float tmp[M_ * DCH];
    __shared__ float biasc[M_];
    const int i    = blockIdx.x;        // 0..511
    const int slot = i >> 3;            // 0..63
    const int b    = (i & 7) + 8 * (slot & 3);
    const int c    = slot >> 2;         // 0..15 d-chunk
    const int tid  = threadIdx.x;

    // ---- phase 0: zero hid + fold weights for this chunk ----
    for (int p = tid; p < TU * LD; p += 1024) hid[p] = 0u;
    if (tid < M_ * DCH) {               // 64 threads
        const int m = tid >> 3, dl = tid & (DCH - 1), d = c * DCH + dl;
        float wraw = 0.f;
#pragma unroll
        for (int o = 0; o < O_; ++o) wraw += fc_w[m * O_ + o] * conv_w[o * D_ + d];
        const float sc = bn_gamma[d] * rsqrtf(bn_var[d] + BN_EPS);
        const float sh = bn_beta[d] - bn_mean[d] * sc;
        wsm[tid] = wraw * sc;
        tmp[tid] = wraw * sh;
    }
    __syncthreads();
    if (tid < M_) {
        float s = 0.f;                  // chunk bias: exactly once per chunk
#pragma unroll
        for (int d = 0; d < DCH; ++d) s += tmp[tid * DCH + d];
        if (c == 0) {                   // global bias: exactly once per batch
            s += fc_b[tid];
            for (int o = 0; o < O_; ++o) s += fc_w[tid * O_ + o] * conv_b[o];
        }
        biasc[tid] = s;                 // read after the phase-1 end barrier
    }

    // ---- phase 1: scatter-max into LDS, float4 loads, full T ----
    const float* xb = x + (size_t)b * T_ * (D_ + 1);
    const int*   mb = mask + b * T_;
    const float  u0 = tw_uniq[b * TU];

    const int q  = tid & 1;           // half lane: d = c*8 + q*4 .. +3
    const int rr = tid >> 1;          // 0..511: row group
    // 4096 rows = 8 passes of 512 rows = 2 outer x UB inner
    for (int it = 0; it < T_ / 512 / UB; ++it) {
        f4u   fv[UB];
        float twf[UB];
        int   mk[UB];
#pragma unroll
        for (int j = 0; j < UB; ++j) {
            const int t = (it * UB + j) * 512 + rr;
            const float* row = xb + (size_t)t * (D_ + 1);
            fv[j]  = *(const f4u*)(row + 1 + c * DCH + q * 4);
            twf[j] = row[0];
            mk[j]  = mb[t];
        }
#pragma unroll
        for (int j = 0; j < UB; ++j) {
            if (mk[j] != 0) {
                int u = min(max((int)(twf[j] - u0), 0), TU - 1);
                unsigned* hp = &hid[u * LD + q * 4];
                if (fv[j].x > 0.0f) atomicMax(hp + 0, __float_as_uint(fv[j].x));
                if (fv[j].y > 0.0f) atomicMax(hp + 1, __float_as_uint(fv[j].y));
                if (fv[j].z > 0.0f) atomicMax(hp + 2, __float_as_uint(fv[j].z));
                if (fv[j].w > 0.0f) atomicMax(hp + 3, __float_as_uint(fv[j].w));
            }
        }
    }
    __syncthreads();

    // ---- phase 2: partial matmul + bias, plain 16 B store to ws ----
    const int u  = tid & (TU - 1);
    const int mh = tid >> 9;          // 0/1 -> m in [4*mh, 4*mh+4)
    float a0 = biasc[mh * 4 + 0];
    float a1 = biasc[mh * 4 + 1];
    float a2 = biasc[mh * 4 + 2];
    float a3 = biasc[mh * 4 + 3];
#pragma unroll
    for (int d = 0; d < DCH; ++d) {
        float hv = __uint_as_float(hid[u * LD + d]);  // stride 9: 2-way, free
        a0 += hv * wsm[(mh * 4 + 0) * DCH + d];
        a1 += hv * wsm[(mh * 4 + 1) * DCH + d];
        a2 += hv * wsm[(mh * 4 + 2) * DCH + d];
        a3 += hv * wsm[(mh * 4 + 3) * DCH + d];
    }
    float4 av = make_float4(a0, a1, a2, a3);
    float* wp = ws + (size_t)c * WS_STRIDE + ((size_t)(b * TU + u)) * M_ + mh * 4;
    *(float4*)wp = av;                // 16 B aligned: index is a multiple of 4
}

// ---------------------------------------------------------------------------
// K2: out[b,u,m] = sum_c partials[c][b][u][m]. 512 blocks x 256 threads,
// 1 element/thread. XCD swizzle matches K1 so batch b's partials are L2-hits:
//   block j: s=j>>3; b=(j&7)+8*(s&3); u-chunk s>>2 (32 u each)
// ---------------------------------------------------------------------------
__global__ __launch_bounds__(256) void reduce_kernel(
    const float* __restrict__ ws, float* __restrict__ out) {
    const int j = blockIdx.x;
    const int s = j >> 3;
    const int b = (j & 7) + 8 * (s & 3);
    const int uc = s >> 2;                       // 0..15
    const int idx = (b * TU + uc * 32) * M_ + threadIdx.x;  // 32 u x 8 m = 256
    float acc = 0.f;
#pragma unroll
    for (int p = 0; p < NP; ++p) acc += ws[(size_t)p * WS_STRIDE + idx];
    out[idx] = acc;
}

extern "C" void kernel_launch(void* const* d_in, const int* in_sizes, int n_in,
                              void* d_out, int out_size, void* d_ws, size_t ws_size,
                              hipStream_t stream) {
    const float* x        = (const float*)d_in[0];   // (32,4096,129) f32
    const int*   mask     = (const int*)  d_in[1];   // (32,4096,1) bool->int32
    const float* tw_uniq  = (const float*)d_in[2];   // (32,512,1) f32
    const float* bn_gamma = (const float*)d_in[3];
    const float* bn_beta  = (const float*)d_in[4];
    const float* bn_mean  = (const float*)d_in[5];
    const float* bn_var   = (const float*)d_in[6];
    const float* conv_w   = (const float*)d_in[7];   // (64,128)
    const float* conv_b   = (const float*)d_in[8];   // (64,)
    const float* fc_w     = (const float*)d_in[9];   // (8,64)
    const float* fc_b     = (const float*)d_in[10];  // (8,)
    float* ws  = (float*)d_ws;                       // needs 8 MB
    float* out = (float*)d_out;                      // (32,512,8) f32

    fused_scatter_mm_kernel<<<512, 1024, 0, stream>>>(
        x, mask, tw_uniq, bn_gamma, bn_beta, bn_mean, bn_var,
        conv_w, conv_b, fc_w, fc_b, ws);
    reduce_kernel<<<512, 256, 0, stream>>>(ws, out);
}

// Round 9
// 132.442 us; speedup vs baseline: 1.0547x; 1.0547x over previous
//
#include <hip/hip_runtime.h>
#include <stdint.h>

// Problem constants (from reference setup_inputs)
#define B_   32
#define T_   4096
#define D_   128
#define TU   512
#define M_   8
#define O_   64      // Dout
#define DCH  16      // D-chunk per block (R5 shape: 8 chunks, disjoint d)
#define NCH  8       // number of D-chunks
#define NP   NCH     // 8 partials per batch (disjoint d -> reduce SUM exact)
#define PAD  17      // hid leading dim: conflict-free in epilogue
#define BN_EPS 1e-5f

#define NWAVE 16
#define TROWS 64                         // rows staged per wave-tile (= lanes)
#define NTILE (T_ / (NWAVE * TROWS))     // 4 tiles per wave

// LDS word layout (one flat array):
//   [0, 8704)            hid[512][17]
//   [8704, 8704+16*1152) per-wave staging: 4x256 feat regions + 64 tw + 64 mask
#define HID_WORDS  (TU * PAD)            // 8704
#define WREG_WORDS 1152
#define LDS_WORDS  (HID_WORDS + NWAVE * WREG_WORDS)   // 27136 words = 108.5 KB

// ws layout: partials[c][b][u][m]; NP*B_*TU*M_ floats = 4 MB
#define WS_STRIDE (B_ * TU * M_)

typedef const __attribute__((address_space(1))) void* gptr_t;
typedef __attribute__((address_space(3))) void* lptr_t;

// ---------------------------------------------------------------------------
// K1: per-(batch b, chunk c) block, full T (max over T stays in one block).
//   phase 0: zero hid; fold BN+conv+fc for this 16-wide chunk (Weff, bias)
//   phase 1: per wave, per 64-row tile: async-DMA the rows' 64 B feat windows
//            + tw + mask into this wave's LDS staging region
//            (global_load_lds: per-lane global addr, LDS dst = base+lane*size;
//            zero VGPR cost -> ~4.6 KB in flight per wave), s_waitcnt vmcnt(0)
//            (wave-local, no barrier), then lane l scatters row l:
//            atomicMax hid[u*17+d] with uint bits (hidden init=0 => only fv>0
//            matter; uint atomicMax == float max for non-negative floats).
//   phase 2: partial[u][m] = biasc[m] + sum_{d in chunk} hid[u][d]*Weff[m][d]
//            stored (non-atomic, 16 B) to ws[c][b][u][m].
//
// XCD swizzle: block i -> xcd = i&7; all 8 chunk-blocks of a batch share one
// XCD so each 516 B x-row is fetched from HBM once:
//   b = (i&7) + 8*((i>>3)&3) ; c = i>>5
// ---------------------------------------------------------------------------
__global__ __launch_bounds__(1024) void fused_scatter_mm_kernel(
    const float* __restrict__ x,        // (B,T,129): [...,0]=tw, [...,1:]=feats
    const int*   __restrict__ mask,     // (B,T) as int32
    const float* __restrict__ tw_uniq,  // (B,Tu)
    const float* __restrict__ bn_gamma,
    const float* __restrict__ bn_beta,
    const float* __restrict__ bn_mean,
    const float* __restrict__ bn_var,
    const float* __restrict__ conv_w,   // (64,128)
    const float* __restrict__ conv_b,   // (64,)
    const float* __restrict__ fc_w,     // (8,64)
    const float* __restrict__ fc_b,     // (8,)
    float*       __restrict__ ws) {     // partials[c][b][u][m]
    __shared__ unsigned lds[LDS_WORDS]; // hid + staging, 108.5 KB
    __shared__ float wsm[M_ * DCH];
    __shared__ float tmp[M_ * DCH];
    __shared__ float biasc[M_];
    const int i   = blockIdx.x;         // 0..255
    const int b   = (i & 7) + 8 * ((i >> 3) & 3);
    const int c   = i >> 5;             // 0..7
    const int tid = threadIdx.x;

    // ---- phase 0: zero hid + fold weights for this chunk ----
    for (int p = tid; p < HID_WORDS; p += 1024) lds[p] = 0u;
    if (tid < M_ * DCH) {               // 128 threads
        const int m = tid >> 4, dl = tid & (DCH - 1), d = c * DCH + dl;
        float wraw = 0.f;
#pragma unroll
        for (int o = 0; o < O_; ++o) wraw += fc_w[m * O_ + o] * conv_w[o * D_ + d];
        const float sc = bn_gamma[d] * rsqrtf(bn_var[d] + BN_EPS);
        const float sh = bn_beta[d] - bn_mean[d] * sc;
        wsm[tid] = wraw * sc;
        tmp[tid] = wraw * sh;
    }
    __syncthreads();
    if (tid < M_) {
        float s = 0.f;                  // chunk bias: exactly once per chunk
#pragma unroll
        for (int d = 0; d < DCH; ++d) s += tmp[tid * DCH + d];
        if (c == 0) {                   // global bias: exactly once per batch
            s += fc_b[tid];
            for (int o = 0; o < O_; ++o) s += fc_w[tid * O_ + o] * conv_b[o];
        }
        biasc[tid] = s;                 // read after the phase-1 end barrier
    }

    // ---- phase 1: async-staged scatter-max ----
    const float* xb = x + (size_t)b * T_ * (D_ + 1);
    const int*   mb = mask + b * T_;
    const float  u0 = tw_uniq[b * TU];

    const int w = tid >> 6;             // wave 0..15 (wave-uniform)
    const int l = tid & 63;             // lane
    unsigned* wreg = &lds[HID_WORDS + w * WREG_WORDS];

    for (int t = 0; t < NTILE; ++t) {
        const int row = (t * NWAVE + w) * TROWS + l;
        const float* rp = xb + (size_t)row * (D_ + 1);
        asm volatile("" ::: "memory");  // keep prior-tile LDS reads before re-stage
        // 6 DMAs: 4x16B feats + 4B tw + 4B mask per lane (no VGPR round-trip)
#pragma unroll
        for (int k = 0; k < 4; ++k) {
            __builtin_amdgcn_global_load_lds(
                (gptr_t)(const void*)(rp + 1 + c * DCH + 4 * k),
                (lptr_t)(void*)(wreg + k * 256), 16, 0, 0);
        }
        __builtin_amdgcn_global_load_lds(
            (gptr_t)(const void*)rp, (lptr_t)(void*)(wreg + 1024), 4, 0, 0);
        __builtin_amdgcn_global_load_lds(
            (gptr_t)(const void*)(mb + row), (lptr_t)(void*)(wreg + 1088), 4, 0, 0);
        __builtin_amdgcn_s_waitcnt(0x0F70);   // vmcnt(0) only (wave-local)
        asm volatile("" ::: "memory");
        // lane l consumes row l of the staged tile
        float4 f[4];
#pragma unroll
        for (int k = 0; k < 4; ++k)
            f[k] = *(const float4*)&wreg[k * 256 + 4 * l];   // ds_read_b128
        const float twv = __uint_as_float(wreg[1024 + l]);
        const int   mkv = (int)wreg[1088 + l];
        if (mkv != 0) {
            const int u = min(max((int)(twv - u0), 0), TU - 1);
            unsigned* hp = &lds[u * PAD];
#pragma unroll
            for (int k = 0; k < 4; ++k) {
                if (f[k].x > 0.0f) atomicMax(hp + 4 * k + 0, __float_as_uint(f[k].x));
                if (f[k].y > 0.0f) atomicMax(hp + 4 * k + 1, __float_as_uint(f[k].y));
                if (f[k].z > 0.0f) atomicMax(hp + 4 * k + 2, __float_as_uint(f[k].z));
                if (f[k].w > 0.0f) atomicMax(hp + 4 * k + 3, __float_as_uint(f[k].w));
            }
        }
    }
    __syncthreads();

    // ---- phase 2: partial matmul + bias, plain 16 B store to ws ----
    const int u  = tid & (TU - 1);
    const int mh = tid >> 9;          // 0/1 -> m in [4*mh, 4*mh+4)
    float a0 = biasc[mh * 4 + 0];
    float a1 = biasc[mh * 4 + 1];
    float a2 = biasc[mh * 4 + 2];
    float a3 = biasc[mh * 4 + 3];
#pragma unroll
    for (int d = 0; d < DCH; ++d) {
        float hv = __uint_as_float(lds[u * PAD + d]);  // stride 17: conflict-free
        a0 += hv * wsm[(mh * 4 + 0) * DCH + d];
        a1 += hv * wsm[(mh * 4 + 1) * DCH + d];
        a2 += hv * wsm[(mh * 4 + 2) * DCH + d];
        a3 += hv * wsm[(mh * 4 + 3) * DCH + d];
    }
    float4 av = make_float4(a0, a1, a2, a3);
    float* wp = ws + (size_t)c * WS_STRIDE + ((size_t)(b * TU + u)) * M_ + mh * 4;
    *(float4*)wp = av;                // 16 B aligned: index is a multiple of 4
}

// ---------------------------------------------------------------------------
// K2: out[b,u,m] = sum_c partials[c][b][u][m]. 512 blocks x 256 threads,
// 1 element/thread. XCD swizzle matches K1 so batch b's partials are L2-hits.
// ---------------------------------------------------------------------------
__global__ __launch_bounds__(256) void reduce_kernel(
    const float* __restrict__ ws, float* __restrict__ out) {
    const int j = blockIdx.x;
    const int s = j >> 3;
    const int b = (j & 7) + 8 * (s & 3);
    const int uc = s >> 2;                       // 0..15
    const int idx = (b * TU + uc * 32) * M_ + threadIdx.x;  // 32 u x 8 m = 256
    float acc = 0.f;
#pragma unroll
    for (int p = 0; p < NP; ++p) acc += ws[(size_t)p * WS_STRIDE + idx];
    out[idx] = acc;
}

extern "C" void kernel_launch(void* const* d_in, const int* in_sizes, int n_in,
                              void* d_out, int out_size, void* d_ws, size_t ws_size,
                              hipStream_t stream) {
    const float* x        = (const float*)d_in[0];   // (32,4096,129) f32
    const int*   mask     = (const int*)  d_in[1];   // (32,4096,1) bool->int32
    const float* tw_uniq  = (const float*)d_in[2];   // (32,512,1) f32
    const float* bn_gamma = (const float*)d_in[3];
    const float* bn_beta  = (const float*)d_in[4];
    const float* bn_mean  = (const float*)d_in[5];
    const float* bn_var   = (const float*)d_in[6];
    const float* conv_w   = (const float*)d_in[7];   // (64,128)
    const float* conv_b   = (const float*)d_in[8];   // (64,)
    const float* fc_w     = (const float*)d_in[9];   // (8,64)
    const float* fc_b     = (const float*)d_in[10];  // (8,)
    float* ws  = (float*)d_ws;                       // needs 4 MB
    float* out = (float*)d_out;                      // (32,512,8) f32

    fused_scatter_mm_kernel<<<256, 1024, 0, stream>>>(
        x, mask, tw_uniq, bn_gamma, bn_beta, bn_mean, bn_var,
        conv_w, conv_b, fc_w, fc_b, ws);
    reduce_kernel<<<512, 256, 0, stream>>>(ws, out);
}

// Round 10
// 129.908 us; speedup vs baseline: 1.0753x; 1.0195x over previous
//
#include <hip/hip_runtime.h>

// Problem constants (from reference setup_inputs)
#define B_   32
#define T_   4096
#define D_   128
#define TU   512
#define M_   8
#define O_   64      // Dout
#define DCH  16      // D-chunk per block (R5 shape: 8 chunks, disjoint d)
#define NCH  8       // number of D-chunks
#define NP   NCH     // 8 partials per batch (disjoint d -> reduce SUM exact)
#define PAD  17      // hid leading dim: conflict-free in both phases
#define BN_EPS 1e-5f
#define UB   8       // t-loop load batch depth; asm barrier forces all 24
                     // loads to issue before first consume (~12 KB in flight
                     // per wave -> MLP the compiler refused to give us)

// 16 B vector with 4 B alignment: x rows are 516 B so the 16 B feat windows
// are only element-aligned; this type lets the compiler emit dwordx4 legally
// (gfx950 unaligned-access-mode handles the line straddle in HW).
typedef float f4u __attribute__((ext_vector_type(4), aligned(4)));

// ws layout: partials[c][b][u][m]; NP*B_*TU*M_ floats = 4 MB
#define WS_STRIDE (B_ * TU * M_)

// ---------------------------------------------------------------------------
// K1: per-(batch b, chunk c) block, full T (max over T stays in one block):
//   phase 0: zero LDS hid; fold BN+conv+fc for this 16-wide chunk
//   phase 1: scatter-max masked positive feats into LDS hid (uint bits;
//            hidden init=0 => only fv>0 matter; uint atomicMax == float max
//            for non-negative floats). UB=8 load batch, asm memory barrier
//            between loads and consumes: memory ops can't cross the clobber,
//            so all 24 loads issue first (defeats compiler load-sinking that
//            kept VGPR=32 / ~2 loads in flight for three rounds).
//   phase 2: partial[u][m] = biasc[m] + sum_{d in chunk} hid[u][d]*Weff[m][d]
//            stored (non-atomic, 16 B) to ws[c][b][u][m].
// Partials are disjoint in d, so the reduce's SUM is exact (R5 algebra).
//
// XCD swizzle: block i -> xcd = i&7; all 8 chunk-blocks of a batch share one
// XCD so each 516 B x-row is fetched from HBM once:
//   b = (i&7) + 8*((i>>3)&3) ; c = i>>5
// ---------------------------------------------------------------------------
__global__ __launch_bounds__(1024) void fused_scatter_mm_kernel(
    const float* __restrict__ x,        // (B,T,129): [...,0]=tw, [...,1:]=feats
    const int*   __restrict__ mask,     // (B,T) as int32
    const float* __restrict__ tw_uniq,  // (B,Tu)
    const float* __restrict__ bn_gamma,
    const float* __restrict__ bn_beta,
    const float* __restrict__ bn_mean,
    const float* __restrict__ bn_var,
    const float* __restrict__ conv_w,   // (64,128)
    const float* __restrict__ conv_b,   // (64,)
    const float* __restrict__ fc_w,     // (8,64)
    const float* __restrict__ fc_b,     // (8,)
    float*       __restrict__ ws) {     // partials[c][b][u][m]
    __shared__ unsigned hid[TU * PAD];  // 34,816 B
    __shared__ float wsm[M_ * DCH];
    __shared__ float tmp[M_ * DCH];
    __shared__ float biasc[M_];
    const int i   = blockIdx.x;         // 0..255
    const int b   = (i & 7) + 8 * ((i >> 3) & 3);
    const int c   = i >> 5;             // 0..7
    const int tid = threadIdx.x;

    // ---- phase 0: zero hid + fold weights for this chunk ----
    for (int p = tid; p < TU * PAD; p += 1024) hid[p] = 0u;
    if (tid < M_ * DCH) {               // 128 threads
        const int m = tid >> 4, dl = tid & (DCH - 1), d = c * DCH + dl;
        float wraw = 0.f;
#pragma unroll
        for (int o = 0; o < O_; ++o) wraw += fc_w[m * O_ + o] * conv_w[o * D_ + d];
        const float sc = bn_gamma[d] * rsqrtf(bn_var[d] + BN_EPS);
        const float sh = bn_beta[d] - bn_mean[d] * sc;
        wsm[tid] = wraw * sc;
        tmp[tid] = wraw * sh;
    }
    __syncthreads();
    if (tid < M_) {
        float s = 0.f;                  // chunk bias: exactly once per chunk
#pragma unroll
        for (int d = 0; d < DCH; ++d) s += tmp[tid * DCH + d];
        if (c == 0) {                   // global bias: exactly once per batch
            s += fc_b[tid];
            for (int o = 0; o < O_; ++o) s += fc_w[tid * O_ + o] * conv_b[o];
        }
        biasc[tid] = s;                 // read after the phase-1 end barrier
    }

    // ---- phase 1: scatter-max into LDS, float4 loads, forced clustering ----
    const float* xb = x + (size_t)b * T_ * (D_ + 1);
    const int*   mb = mask + b * T_;
    const float  u0 = tw_uniq[b * TU];

    const int q  = tid & 3;           // quad lane: d = c*16 + q*4 .. +3
    const int rr = tid >> 2;          // 0..255: row group
    // 4096 rows = 16 passes of 256 rows = 2 outer x UB inner
    for (int it = 0; it < T_ / 256 / UB; ++it) {
        f4u   fv[UB];
        float twf[UB];
        int   mk[UB];
#pragma unroll
        for (int j = 0; j < UB; ++j) {
            const int t = (it * UB + j) * 256 + rr;
            const float* row = xb + (size_t)t * (D_ + 1);
            fv[j]  = *(const f4u*)(row + 1 + c * DCH + q * 4);
            twf[j] = row[0];
            mk[j]  = mb[t];
        }
        // Loads above cannot sink past this; atomics below cannot hoist above.
        asm volatile("" ::: "memory");
#pragma unroll
        for (int j = 0; j < UB; ++j) {
            if (mk[j] != 0) {
                int u = min(max((int)(twf[j] - u0), 0), TU - 1);
                unsigned* hp = &hid[u * PAD + q * 4];
                if (fv[j].x > 0.0f) atomicMax(hp + 0, __float_as_uint(fv[j].x));
                if (fv[j].y > 0.0f) atomicMax(hp + 1, __float_as_uint(fv[j].y));
                if (fv[j].z > 0.0f) atomicMax(hp + 2, __float_as_uint(fv[j].z));
                if (fv[j].w > 0.0f) atomicMax(hp + 3, __float_as_uint(fv[j].w));
            }
        }
    }
    __syncthreads();

    // ---- phase 2: partial matmul + bias, plain 16 B store to ws ----
    const int u  = tid & (TU - 1);
    const int mh = tid >> 9;          // 0/1 -> m in [4*mh, 4*mh+4)
    float a0 = biasc[mh * 4 + 0];
    float a1 = biasc[mh * 4 + 1];
    float a2 = biasc[mh * 4 + 2];
    float a3 = biasc[mh * 4 + 3];
#pragma unroll
    for (int d = 0; d < DCH; ++d) {
        float hv = __uint_as_float(hid[u * PAD + d]);  // stride 17: conflict-free
        a0 += hv * wsm[(mh * 4 + 0) * DCH + d];
        a1 += hv * wsm[(mh * 4 + 1) * DCH + d];
        a2 += hv * wsm[(mh * 4 + 2) * DCH + d];
        a3 += hv * wsm[(mh * 4 + 3) * DCH + d];
    }
    float4 av = make_float4(a0, a1, a2, a3);
    float* wp = ws + (size_t)c * WS_STRIDE + ((size_t)(b * TU + u)) * M_ + mh * 4;
    *(float4*)wp = av;                // 16 B aligned: index is a multiple of 4
}

// ---------------------------------------------------------------------------
// K2: out[b,u,m] = sum_c partials[c][b][u][m]. 512 blocks x 256 threads,
// 1 element/thread. XCD swizzle matches K1 so batch b's partials are L2-hits.
// ---------------------------------------------------------------------------
__global__ __launch_bounds__(256) void reduce_kernel(
    const float* __restrict__ ws, float* __restrict__ out) {
    const int j = blockIdx.x;
    const int s = j >> 3;
    const int b = (j & 7) + 8 * (s & 3);
    const int uc = s >> 2;                       // 0..15
    const int idx = (b * TU + uc * 32) * M_ + threadIdx.x;  // 32 u x 8 m = 256
    float acc = 0.f;
#pragma unroll
    for (int p = 0; p < NP; ++p) acc += ws[(size_t)p * WS_STRIDE + idx];
    out[idx] = acc;
}

extern "C" void kernel_launch(void* const* d_in, const int* in_sizes, int n_in,
                              void* d_out, int out_size, void* d_ws, size_t ws_size,
                              hipStream_t stream) {
    const float* x        = (const float*)d_in[0];   // (32,4096,129) f32
    const int*   mask     = (const int*)  d_in[1];   // (32,4096,1) bool->int32
    const float* tw_uniq  = (const float*)d_in[2];   // (32,512,1) f32
    const float* bn_gamma = (const float*)d_in[3];
    const float* bn_beta  = (const float*)d_in[4];
    const float* bn_mean  = (const float*)d_in[5];
    const float* bn_var   = (const float*)d_in[6];
    const float* conv_w   = (const float*)d_in[7];   // (64,128)
    const float* conv_b   = (const float*)d_in[8];   // (64,)
    const float* fc_w     = (const float*)d_in[9];   // (8,64)
    const float* fc_b     = (const float*)d_in[10];  // (8,)
    float* ws  = (float*)d_ws;                       // needs 4 MB
    float* out = (float*)d_out;                      // (32,512,8) f32

    fused_scatter_mm_kernel<<<256, 1024, 0, stream>>>(
        x, mask, tw_uniq, bn_gamma, bn_beta, bn_mean, bn_var,
        conv_w, conv_b, fc_w, fc_b, ws);
    reduce_kernel<<<512, 256, 0, stream>>>(ws, out);
}